// Round 3
// baseline (295.701 us; speedup 1.0000x reference)
//
#include <hip/hip_runtime.h>
#include <hip/hip_fp16.h>

// Problem constants (match reference):
//   attrs:    [8, 10000, 3, 16] fp32   (flat face table of 80000 faces x 48 floats)
//   baryw:    [8, 512, 512, 3]  fp32
//   triangle: [8, 512, 512]     int32  (-1 = background; indexes flat [BZ*NF])
//   out:      [8, 17, 512, 512] fp32   (16 interpolated channels + visibility)
//
// R5 strategy: R4 (single-sweep) landed at ~64 us render vs ~29 us byte
// roofline -> TA request rate is the limiter. Each pixel's 128 B record was
// loaded with 6 separate dwordx4 gathers = 6 line lookups/pixel (12.6M total;
// ~20 us of TA serialization). Fix: WAVE-COOPERATIVE GATHER - lane i fetches
// segment (i&7) of record-slot (i>>3), so one instruction covers 8 full
// records = 8 line lookups (1 per pixel, 6x fewer). Records are staged in a
// 32 KB XOR-swizzled LDS buffer (seg ^= slot&7 kills the 128B-stride bank
// conflict); owners read their 6 int4 from LDS and accumulate. Face ids
// staged once in 4 KB LDS. Keep the 4-phase L2-residency sweep (R3's win)
// as a predicate on the cooperative load. 36 KB LDS + <=128 VGPR -> 4
// blocks/CU = 16 waves/CU.
constexpr int BZ = 8, NF = 10000, D = 16, HImg = 512, WImg = 512;
constexpr int HW = HImg * WImg;          // 262144
constexpr int NPIX = BZ * HW;            // 2097152
constexpr int NFACES = BZ * NF;          // 80000
constexpr int PIX_PER_THREAD = 4;
constexpr int NTHREADS = NPIX / PIX_PER_THREAD;  // 524288
constexpr int BLOCK = 256;
// fp16 record: 3 vertices x 16 ch x 2 B = 96 B, padded to 128 B (one line).
constexpr size_t REC_USHORTS = 64;       // 128 B / 2
constexpr size_t WS_NEEDED = (size_t)NFACES * 128;

constexpr int NPHASE = 4;
constexpr int FACES_PER_PHASE = NFACES / NPHASE;  // 20000 -> 2.56 MB/phase

typedef float f32x4 __attribute__((ext_vector_type(4)));
typedef int   i32x4 __attribute__((ext_vector_type(4)));

// ---- pass 1: fp32 attrs -> fp16 padded records --------------------------
__global__ __launch_bounds__(BLOCK) void convert_kernel(
    const float* __restrict__ attrs, ushort* __restrict__ rec)
{
    const int tid = blockIdx.x * BLOCK + threadIdx.x;
    if (tid >= NFACES * 6) return;
    const int face = tid / 6;
    const int c    = tid - face * 6;
    const float4* src = reinterpret_cast<const float4*>(
        attrs + (size_t)face * 48 + c * 8);
    const float4 a = src[0], b = src[1];
    __half h[8];
    h[0] = __float2half_rn(a.x); h[1] = __float2half_rn(a.y);
    h[2] = __float2half_rn(a.z); h[3] = __float2half_rn(a.w);
    h[4] = __float2half_rn(b.x); h[5] = __float2half_rn(b.y);
    h[6] = __float2half_rn(b.z); h[7] = __float2half_rn(b.w);
    *reinterpret_cast<int4*>(rec + (size_t)face * REC_USHORTS + c * 8) =
        *reinterpret_cast<const int4*>(h);
}

__device__ inline void h8_to_f8(int4 raw, float f[8]) {
    const __half2* hp = reinterpret_cast<const __half2*>(&raw);
#pragma unroll
    for (int q = 0; q < 4; ++q) {
        const float2 t = __half22float2(hp[q]);
        f[2 * q]     = t.x;
        f[2 * q + 1] = t.y;
    }
}

// ---- pass 2: phased cooperative-gather render ---------------------------
__global__ __launch_bounds__(BLOCK, 4) void render_coop_kernel(
    const ushort* __restrict__ rec,
    const float*  __restrict__ baryw,
    const int*    __restrict__ tri,
    float*        __restrict__ out)
{
    // slot k of chunk j = thread k's pixel j; record swizzled by seg^(slot&7)
    __shared__ int  s_face[BLOCK * PIX_PER_THREAD];  // 4 KB
    __shared__ int4 s_rec[BLOCK * 8];                // 32 KB

    // grid exactly covers NPIX: no early returns -> __syncthreads() is safe.
    const int tidx = threadIdx.x;
    const int tid  = blockIdx.x * BLOCK + tidx;
    const int p0   = tid * PIX_PER_THREAD;

    const int n   = p0 / HW;
    const int pix = p0 - n * HW;

    // Streamed inputs: nontemporal so they don't evict the face table in L2.
    const i32x4 t4 = __builtin_nontemporal_load(
        reinterpret_cast<const i32x4*>(tri + p0));
    const f32x4* bw = reinterpret_cast<const f32x4*>(baryw + (size_t)p0 * 3);
    const f32x4 b0 = __builtin_nontemporal_load(bw + 0);
    const f32x4 b1 = __builtin_nontemporal_load(bw + 1);
    const f32x4 b2 = __builtin_nontemporal_load(bw + 2);

    float w[PIX_PER_THREAD][3] = {
        {b0.x, b0.y, b0.z},
        {b0.w, b1.x, b1.y},
        {b1.z, b1.w, b2.x},
        {b2.y, b2.z, b2.w},
    };
    const int t[PIX_PER_THREAD] = {t4.x, t4.y, t4.z, t4.w};

    float vis[PIX_PER_THREAD];
#pragma unroll
    for (int j = 0; j < PIX_PER_THREAD; ++j) {
        const bool bg = (t[j] < 0);
        vis[j] = bg ? 0.0f : 1.0f;
        w[j][0] *= vis[j];
        w[j][1] *= vis[j];
        w[j][2] *= vis[j];
        s_face[tidx * PIX_PER_THREAD + j] = t[j];
    }
    __syncthreads();

    const int4* rec4 = reinterpret_cast<const int4*>(rec);

    float r[PIX_PER_THREAD][D];
#pragma unroll
    for (int j = 0; j < PIX_PER_THREAD; ++j)
#pragma unroll
        for (int i = 0; i < D; ++i) r[j][i] = 0.0f;

    const int krec = tidx >> 3;   // record-slot base within a pass (0..31)
    const int seg  = tidx & 7;    // segment of the 128 B record (0..7)

    for (int ph = 0; ph < NPHASE; ++ph) {
        const int lo = ph * FACES_PER_PHASE;
#pragma unroll
        for (int j = 0; j < PIX_PER_THREAD; ++j) {
            // --- cooperative load of chunk j (256 records) ---------------
            // one wave instruction covers 8 whole records -> 8 line lookups
#pragma unroll
            for (int pass = 0; pass < 8; ++pass) {
                const int slot = pass * 32 + krec;          // 0..255
                const int f = s_face[slot * PIX_PER_THREAD + j];
                if ((unsigned)(f - lo) < (unsigned)FACES_PER_PHASE) {
                    const int4 v = rec4[(size_t)f * 8 + seg];
                    s_rec[slot * 8 + (seg ^ (slot & 7))] = v;
                }
            }
            __syncthreads();
            // --- accumulate own pixel j from LDS -------------------------
            if ((unsigned)(t[j] - lo) < (unsigned)FACES_PER_PHASE) {
                const int sw = tidx & 7;
                float a[8];
                // segs 0,1 = v0 ch0-7/8-15; 2,3 = v1; 4,5 = v2
                h8_to_f8(s_rec[tidx * 8 + (0 ^ sw)], a);
#pragma unroll
                for (int i = 0; i < 8; ++i) r[j][i]     += w[j][0] * a[i];
                h8_to_f8(s_rec[tidx * 8 + (1 ^ sw)], a);
#pragma unroll
                for (int i = 0; i < 8; ++i) r[j][8 + i] += w[j][0] * a[i];
                h8_to_f8(s_rec[tidx * 8 + (2 ^ sw)], a);
#pragma unroll
                for (int i = 0; i < 8; ++i) r[j][i]     += w[j][1] * a[i];
                h8_to_f8(s_rec[tidx * 8 + (3 ^ sw)], a);
#pragma unroll
                for (int i = 0; i < 8; ++i) r[j][8 + i] += w[j][1] * a[i];
                h8_to_f8(s_rec[tidx * 8 + (4 ^ sw)], a);
#pragma unroll
                for (int i = 0; i < 8; ++i) r[j][i]     += w[j][2] * a[i];
                h8_to_f8(s_rec[tidx * 8 + (5 ^ sw)], a);
#pragma unroll
                for (int i = 0; i < 8; ++i) r[j][8 + i] += w[j][2] * a[i];
            }
            __syncthreads();   // protect s_rec before next chunk overwrites
        }
    }

    // deferred store burst: all 17 channels after the gather phases.
    const size_t outbase = (size_t)n * (D + 1) * HW + pix;
#pragma unroll
    for (int d = 0; d < D; ++d) {
        f32x4 o;
        o.x = r[0][d]; o.y = r[1][d]; o.z = r[2][d]; o.w = r[3][d];
        __builtin_nontemporal_store(
            o, reinterpret_cast<f32x4*>(out + outbase + (size_t)d * HW));
    }
    f32x4 v;
    v.x = vis[0]; v.y = vis[1]; v.z = vis[2]; v.w = vis[3];
    __builtin_nontemporal_store(
        v, reinterpret_cast<f32x4*>(out + outbase + (size_t)D * HW));
}

// ---- fallback: direct fp32 path (R1 kernel) -----------------------------
__global__ __launch_bounds__(BLOCK) void renderer_f32_kernel(
    const float* __restrict__ attrs,
    const float* __restrict__ baryw,
    const int*   __restrict__ tri,
    float*       __restrict__ out)
{
    const int tid = blockIdx.x * BLOCK + threadIdx.x;
    const int p0  = tid * PIX_PER_THREAD;
    if (p0 >= NPIX) return;

    const int n   = p0 / HW;
    const int pix = p0 - n * HW;

    const int4 t4 = *reinterpret_cast<const int4*>(tri + p0);
    const float4* bw = reinterpret_cast<const float4*>(baryw + (size_t)p0 * 3);
    const float4 b0 = bw[0], b1 = bw[1], b2 = bw[2];

    float w[PIX_PER_THREAD][3] = {
        {b0.x, b0.y, b0.z},
        {b0.w, b1.x, b1.y},
        {b1.z, b1.w, b2.x},
        {b2.y, b2.z, b2.w},
    };
    const int t[PIX_PER_THREAD] = {t4.x, t4.y, t4.z, t4.w};

    float vis[PIX_PER_THREAD];
    const float4* abase[PIX_PER_THREAD];
#pragma unroll
    for (int j = 0; j < PIX_PER_THREAD; ++j) {
        const bool bg = (t[j] < 0);
        vis[j] = bg ? 0.0f : 1.0f;
        const int tc = bg ? 0 : t[j];
        abase[j] = reinterpret_cast<const float4*>(attrs + (size_t)tc * (3 * D));
        w[j][0] *= vis[j];
        w[j][1] *= vis[j];
        w[j][2] *= vis[j];
    }

    const size_t outbase = (size_t)n * (D + 1) * HW + pix;

#pragma unroll
    for (int c = 0; c < 4; ++c) {
        float r[PIX_PER_THREAD][4];
#pragma unroll
        for (int j = 0; j < PIX_PER_THREAD; ++j) {
            const float4 a0 = abase[j][c];
            const float4 a1 = abase[j][4 + c];
            const float4 a2 = abase[j][8 + c];
            r[j][0] = w[j][0] * a0.x + w[j][1] * a1.x + w[j][2] * a2.x;
            r[j][1] = w[j][0] * a0.y + w[j][1] * a1.y + w[j][2] * a2.y;
            r[j][2] = w[j][0] * a0.z + w[j][1] * a1.z + w[j][2] * a2.z;
            r[j][3] = w[j][0] * a0.w + w[j][1] * a1.w + w[j][2] * a2.w;
        }
#pragma unroll
        for (int i = 0; i < 4; ++i) {
            const int d = c * 4 + i;
            float4 o;
            o.x = r[0][i]; o.y = r[1][i]; o.z = r[2][i]; o.w = r[3][i];
            *reinterpret_cast<float4*>(out + outbase + (size_t)d * HW) = o;
        }
    }

    float4 v;
    v.x = vis[0]; v.y = vis[1]; v.z = vis[2]; v.w = vis[3];
    *reinterpret_cast<float4*>(out + outbase + (size_t)D * HW) = v;
}

extern "C" void kernel_launch(void* const* d_in, const int* in_sizes, int n_in,
                              void* d_out, int out_size, void* d_ws, size_t ws_size,
                              hipStream_t stream) {
    const float* attrs = (const float*)d_in[0];
    const float* baryw = (const float*)d_in[1];
    const int*   tri   = (const int*)d_in[2];
    float*       out   = (float*)d_out;

    const int grid = NTHREADS / BLOCK;  // 2048 blocks

    if (ws_size >= WS_NEEDED) {
        ushort* rec = (ushort*)d_ws;
        const int conv_grid = (NFACES * 6 + BLOCK - 1) / BLOCK;  // 1875
        convert_kernel<<<conv_grid, BLOCK, 0, stream>>>(attrs, rec);
        render_coop_kernel<<<grid, BLOCK, 0, stream>>>(rec, baryw, tri, out);
    } else {
        renderer_f32_kernel<<<grid, BLOCK, 0, stream>>>(attrs, baryw, tri, out);
    }
}

// Round 4
// 227.534 us; speedup vs baseline: 1.2996x; 1.2996x over previous
//
#include <hip/hip_runtime.h>
#include <hip/hip_fp16.h>

// Problem constants (match reference):
//   attrs:    [8, 10000, 3, 16] fp32   (flat face table of 80000 faces x 48 floats)
//   baryw:    [8, 512, 512, 3]  fp32
//   triangle: [8, 512, 512]     int32  (-1 = background; indexes flat [BZ*NF])
//   out:      [8, 17, 512, 512] fp32   (16 interpolated channels + visibility)
//
// R5 strategy: R3's cooperative gather was right (6x fewer TA line lookups:
// FETCH 165->106 MB) but died from (a) accumulator spill to scratch
// (WRITE 139->245 MB at VGPR_Count=64) and (b) 32 block-wide barriers.
// Fix both structurally:
//   - WAVE-PRIVATE staging: each wave owns an 8 KB LDS slab; face ids are
//     broadcast with __shfl (no shared s_face); producer == consumer wave,
//     so NO __syncthreads in the inner loop (per-wave in-order DS pipe;
//     wave_barrier pins compiler ordering).
//   - PIX_PER_THREAD=2: accumulators 32 VGPRs -> no spill even if the
//     allocator targets 64 total. Grid 4096 blocks = 2 cohorts (less tail).
//   - NPHASE=2 (5.12 MB face range; halves predicated instruction issue).
// Gather stays 1 line lookup per pixel: lane i loads segment (i&7) of
// record-slot (i>>3), 8 whole 128 B records per wave instruction. LDS is
// XOR-swizzled (seg ^ slot&7) so the 128 B-stride readback is conflict-free.
constexpr int BZ = 8, NF = 10000, D = 16, HImg = 512, WImg = 512;
constexpr int HW = HImg * WImg;          // 262144
constexpr int NPIX = BZ * HW;            // 2097152
constexpr int NFACES = BZ * NF;          // 80000
constexpr int PIX_PER_THREAD = 2;
constexpr int NTHREADS = NPIX / PIX_PER_THREAD;  // 1048576
constexpr int BLOCK = 256;
constexpr int WAVES = BLOCK / 64;        // 4
// fp16 record: 3 vertices x 16 ch x 2 B = 96 B, padded to 128 B (one line).
constexpr size_t REC_USHORTS = 64;       // 128 B / 2
constexpr size_t WS_NEEDED = (size_t)NFACES * 128;

constexpr int NPHASE = 2;
constexpr int FACES_PER_PHASE = NFACES / NPHASE;  // 40000 -> 5.12 MB/phase

typedef float f32x2 __attribute__((ext_vector_type(2)));
typedef int   i32x2 __attribute__((ext_vector_type(2)));
typedef float f32x4 __attribute__((ext_vector_type(4)));
typedef int   i32x4 __attribute__((ext_vector_type(4)));

// ---- pass 1: fp32 attrs -> fp16 padded records --------------------------
__global__ __launch_bounds__(BLOCK) void convert_kernel(
    const float* __restrict__ attrs, ushort* __restrict__ rec)
{
    const int tid = blockIdx.x * BLOCK + threadIdx.x;
    if (tid >= NFACES * 6) return;
    const int face = tid / 6;
    const int c    = tid - face * 6;
    const float4* src = reinterpret_cast<const float4*>(
        attrs + (size_t)face * 48 + c * 8);
    const float4 a = src[0], b = src[1];
    __half h[8];
    h[0] = __float2half_rn(a.x); h[1] = __float2half_rn(a.y);
    h[2] = __float2half_rn(a.z); h[3] = __float2half_rn(a.w);
    h[4] = __float2half_rn(b.x); h[5] = __float2half_rn(b.y);
    h[6] = __float2half_rn(b.z); h[7] = __float2half_rn(b.w);
    *reinterpret_cast<int4*>(rec + (size_t)face * REC_USHORTS + c * 8) =
        *reinterpret_cast<const int4*>(h);
}

__device__ inline void h8_to_f8(int4 raw, float f[8]) {
    const __half2* hp = reinterpret_cast<const __half2*>(&raw);
#pragma unroll
    for (int q = 0; q < 4; ++q) {
        const float2 t = __half22float2(hp[q]);
        f[2 * q]     = t.x;
        f[2 * q + 1] = t.y;
    }
}

// ---- pass 2: wave-cooperative phased render -----------------------------
__global__ __launch_bounds__(BLOCK) void render_wavecoop_kernel(
    const ushort* __restrict__ rec,
    const float*  __restrict__ baryw,
    const int*    __restrict__ tri,
    float*        __restrict__ out)
{
    // one 8 KB slab per wave: 64 records x 8 int4, seg index XOR-swizzled
    __shared__ int4 s_rec[WAVES][64 * 8];   // 32 KB

    const int tidx = threadIdx.x;
    const int wid  = tidx >> 6;
    const int lane = tidx & 63;
    const int tid  = blockIdx.x * BLOCK + tidx;
    const int p0   = tid * PIX_PER_THREAD;

    const int n   = p0 / HW;
    const int pix = p0 - n * HW;

    // Streamed inputs: nontemporal so they don't evict the face table in L2.
    const i32x2 t2 = __builtin_nontemporal_load(
        reinterpret_cast<const i32x2*>(tri + p0));
    const f32x2* bw = reinterpret_cast<const f32x2*>(baryw + (size_t)p0 * 3);
    const f32x2 b0 = __builtin_nontemporal_load(bw + 0);
    const f32x2 b1 = __builtin_nontemporal_load(bw + 1);
    const f32x2 b2 = __builtin_nontemporal_load(bw + 2);

    float w[PIX_PER_THREAD][3] = {
        {b0.x, b0.y, b1.x},
        {b1.y, b2.x, b2.y},
    };
    const int t[PIX_PER_THREAD] = {t2.x, t2.y};

    float vis[PIX_PER_THREAD];
#pragma unroll
    for (int j = 0; j < PIX_PER_THREAD; ++j) {
        const bool bg = (t[j] < 0);
        vis[j] = bg ? 0.0f : 1.0f;
        w[j][0] *= vis[j];
        w[j][1] *= vis[j];
        w[j][2] *= vis[j];
    }

    const int4* rec4 = reinterpret_cast<const int4*>(rec);

    float r[PIX_PER_THREAD][D];
#pragma unroll
    for (int j = 0; j < PIX_PER_THREAD; ++j)
#pragma unroll
        for (int i = 0; i < D; ++i) r[j][i] = 0.0f;

    const int seg = lane & 7;       // segment this lane fetches (0..7)
    const int sw  = lane & 7;       // read-side swizzle for own record

    for (int ph = 0; ph < NPHASE; ++ph) {
        const int lo = ph * FACES_PER_PHASE;
#pragma unroll
        for (int j = 0; j < PIX_PER_THREAD; ++j) {
            // --- wave-cooperative load of chunk j (64 records) -----------
            // one wave instruction = 8 whole 128 B records = 8 line lookups
#pragma unroll
            for (int pass = 0; pass < 8; ++pass) {
                const int slot = pass * 8 + (lane >> 3);    // 0..63
                const int f = __shfl(t[j], slot);           // slot's face id
                if ((unsigned)(f - lo) < (unsigned)FACES_PER_PHASE) {
                    s_rec[wid][slot * 8 + (seg ^ (slot & 7))] =
                        rec4[(size_t)f * 8 + seg];
                }
            }
            // producer == consumer wave: per-wave in-order DS pipe makes
            // the readback safe; wave_barrier pins compiler ordering.
            __builtin_amdgcn_wave_barrier();
            // --- accumulate own pixel j from LDS -------------------------
            if ((unsigned)(t[j] - lo) < (unsigned)FACES_PER_PHASE) {
                const int4* sb = &s_rec[wid][lane * 8];
                float a[8];
                // segs 0,1 = v0 ch0-7/8-15; 2,3 = v1; 4,5 = v2
                h8_to_f8(sb[0 ^ sw], a);
#pragma unroll
                for (int i = 0; i < 8; ++i) r[j][i]     += w[j][0] * a[i];
                h8_to_f8(sb[1 ^ sw], a);
#pragma unroll
                for (int i = 0; i < 8; ++i) r[j][8 + i] += w[j][0] * a[i];
                h8_to_f8(sb[2 ^ sw], a);
#pragma unroll
                for (int i = 0; i < 8; ++i) r[j][i]     += w[j][1] * a[i];
                h8_to_f8(sb[3 ^ sw], a);
#pragma unroll
                for (int i = 0; i < 8; ++i) r[j][8 + i] += w[j][1] * a[i];
                h8_to_f8(sb[4 ^ sw], a);
#pragma unroll
                for (int i = 0; i < 8; ++i) r[j][i]     += w[j][2] * a[i];
                h8_to_f8(sb[5 ^ sw], a);
#pragma unroll
                for (int i = 0; i < 8; ++i) r[j][8 + i] += w[j][2] * a[i];
            }
            __builtin_amdgcn_wave_barrier();  // WAR: next chunk overwrites
        }
        // cheap phase-coherence barrier (1 total) so the block's waves keep
        // roughly one 5.12 MB face range live in L2 at a time
        if (ph == 0) __syncthreads();
    }

    // deferred store burst: all 17 channels after the gather phases.
    const size_t outbase = (size_t)n * (D + 1) * HW + pix;
#pragma unroll
    for (int d = 0; d < D; ++d) {
        f32x2 o;
        o.x = r[0][d]; o.y = r[1][d];
        __builtin_nontemporal_store(
            o, reinterpret_cast<f32x2*>(out + outbase + (size_t)d * HW));
    }
    f32x2 v;
    v.x = vis[0]; v.y = vis[1];
    __builtin_nontemporal_store(
        v, reinterpret_cast<f32x2*>(out + outbase + (size_t)D * HW));
}

// ---- fallback: direct fp32 path (R1 kernel) -----------------------------
__global__ __launch_bounds__(BLOCK) void renderer_f32_kernel(
    const float* __restrict__ attrs,
    const float* __restrict__ baryw,
    const int*   __restrict__ tri,
    float*       __restrict__ out)
{
    const int tid = blockIdx.x * BLOCK + threadIdx.x;
    const int p0  = tid * 4;
    if (p0 >= NPIX) return;

    const int n   = p0 / HW;
    const int pix = p0 - n * HW;

    const int4 t4 = *reinterpret_cast<const int4*>(tri + p0);
    const float4* bw = reinterpret_cast<const float4*>(baryw + (size_t)p0 * 3);
    const float4 b0 = bw[0], b1 = bw[1], b2 = bw[2];

    float w[4][3] = {
        {b0.x, b0.y, b0.z},
        {b0.w, b1.x, b1.y},
        {b1.z, b1.w, b2.x},
        {b2.y, b2.z, b2.w},
    };
    const int t[4] = {t4.x, t4.y, t4.z, t4.w};

    float vis[4];
    const float4* abase[4];
#pragma unroll
    for (int j = 0; j < 4; ++j) {
        const bool bg = (t[j] < 0);
        vis[j] = bg ? 0.0f : 1.0f;
        const int tc = bg ? 0 : t[j];
        abase[j] = reinterpret_cast<const float4*>(attrs + (size_t)tc * (3 * D));
        w[j][0] *= vis[j];
        w[j][1] *= vis[j];
        w[j][2] *= vis[j];
    }

    const size_t outbase = (size_t)n * (D + 1) * HW + pix;

#pragma unroll
    for (int c = 0; c < 4; ++c) {
        float r[4][4];
#pragma unroll
        for (int j = 0; j < 4; ++j) {
            const float4 a0 = abase[j][c];
            const float4 a1 = abase[j][4 + c];
            const float4 a2 = abase[j][8 + c];
            r[j][0] = w[j][0] * a0.x + w[j][1] * a1.x + w[j][2] * a2.x;
            r[j][1] = w[j][0] * a0.y + w[j][1] * a1.y + w[j][2] * a2.y;
            r[j][2] = w[j][0] * a0.z + w[j][1] * a1.z + w[j][2] * a2.z;
            r[j][3] = w[j][0] * a0.w + w[j][1] * a1.w + w[j][2] * a2.w;
        }
#pragma unroll
        for (int i = 0; i < 4; ++i) {
            const int d = c * 4 + i;
            float4 o;
            o.x = r[0][i]; o.y = r[1][i]; o.z = r[2][i]; o.w = r[3][i];
            *reinterpret_cast<float4*>(out + outbase + (size_t)d * HW) = o;
        }
    }

    float4 v;
    v.x = vis[0]; v.y = vis[1]; v.z = vis[2]; v.w = vis[3];
    *reinterpret_cast<float4*>(out + outbase + (size_t)D * HW) = v;
}

extern "C" void kernel_launch(void* const* d_in, const int* in_sizes, int n_in,
                              void* d_out, int out_size, void* d_ws, size_t ws_size,
                              hipStream_t stream) {
    const float* attrs = (const float*)d_in[0];
    const float* baryw = (const float*)d_in[1];
    const int*   tri   = (const int*)d_in[2];
    float*       out   = (float*)d_out;

    if (ws_size >= WS_NEEDED) {
        ushort* rec = (ushort*)d_ws;
        const int conv_grid = (NFACES * 6 + BLOCK - 1) / BLOCK;  // 1875
        convert_kernel<<<conv_grid, BLOCK, 0, stream>>>(attrs, rec);
        const int grid = NTHREADS / BLOCK;  // 4096 blocks (2 cohorts)
        render_wavecoop_kernel<<<grid, BLOCK, 0, stream>>>(rec, baryw, tri, out);
    } else {
        const int grid = (NPIX / 4) / BLOCK;
        renderer_f32_kernel<<<grid, BLOCK, 0, stream>>>(attrs, baryw, tri, out);
    }
}

// Round 5
// 212.338 us; speedup vs baseline: 1.3926x; 1.0716x over previous
//
#include <hip/hip_runtime.h>
#include <hip/hip_fp16.h>

// Problem constants (match reference):
//   attrs:    [8, 10000, 3, 16] fp32   (flat face table of 80000 faces x 48 floats)
//   baryw:    [8, 512, 512, 3]  fp32
//   triangle: [8, 512, 512]     int32  (-1 = background; indexes flat [BZ*NF])
//   out:      [8, 17, 512, 512] fp32   (16 interpolated channels + visibility)
//
// R5 strategy: two rounds of evidence say added gather machinery (LDS
// staging, shuffles, extra barriers) loses to R2's plain single-sweep.
// Keep R2's structure EXACTLY; cut TA line-lookups by pure lane remapping:
//   lane l = (h = l>>5 channel-half, q = l&31), pixels 4q..4q+3.
//   Each thread loads only record slots {h, 2+h, 4+h} (3 dwordx4/pixel);
//   lane pair (l, l+32) hits the SAME 64 B sector of the same record line
//   per instruction (offsets 0/16, 32/48, 64/80) -> coalescer merges ->
//   32 distinct lines/instr = 3 lookups/pixel, half of R2's 6.
// tri/baryw duplicated across halves = same-line reads (free at HBM).
// Stores stay full-width: one f32x4 instr covers plane i (lanes 0-31) and
// plane 8+i (lanes 32-63), two contiguous 512 B clusters. Accumulators are
// 32 VGPRs -> no spill. Keep the 4-phase L2-residency sweep + nt streams.
constexpr int BZ = 8, NF = 10000, D = 16, HImg = 512, WImg = 512;
constexpr int HW = HImg * WImg;          // 262144
constexpr int NPIX = BZ * HW;            // 2097152
constexpr int NFACES = BZ * NF;          // 80000
constexpr int PIX_PER_LANE = 4;          // consecutive pixels per lane
constexpr int BLOCK = 256;
// threads: 2 half-channel threads per pixel, 4 pixels per thread
constexpr int NTHREADS = NPIX * 2 / PIX_PER_LANE;   // 1048576
// fp16 record: 3 vertices x 16 ch x 2 B = 96 B, padded to 128 B (one line).
constexpr size_t REC_USHORTS = 64;       // 128 B / 2
constexpr size_t WS_NEEDED = (size_t)NFACES * 128;

constexpr int NPHASE = 4;
constexpr int FACES_PER_PHASE = NFACES / NPHASE;  // 20000 -> 2.56 MB/phase

typedef float f32x4 __attribute__((ext_vector_type(4)));
typedef int   i32x4 __attribute__((ext_vector_type(4)));

// ---- pass 1: fp32 attrs -> fp16 padded records --------------------------
__global__ __launch_bounds__(BLOCK) void convert_kernel(
    const float* __restrict__ attrs, ushort* __restrict__ rec)
{
    const int tid = blockIdx.x * BLOCK + threadIdx.x;
    if (tid >= NFACES * 6) return;
    const int face = tid / 6;
    const int c    = tid - face * 6;
    const float4* src = reinterpret_cast<const float4*>(
        attrs + (size_t)face * 48 + c * 8);
    const float4 a = src[0], b = src[1];
    __half h[8];
    h[0] = __float2half_rn(a.x); h[1] = __float2half_rn(a.y);
    h[2] = __float2half_rn(a.z); h[3] = __float2half_rn(a.w);
    h[4] = __float2half_rn(b.x); h[5] = __float2half_rn(b.y);
    h[6] = __float2half_rn(b.z); h[7] = __float2half_rn(b.w);
    *reinterpret_cast<int4*>(rec + (size_t)face * REC_USHORTS + c * 8) =
        *reinterpret_cast<const int4*>(h);
}

__device__ inline void h8_to_f8(int4 raw, float f[8]) {
    const __half2* hp = reinterpret_cast<const __half2*>(&raw);
#pragma unroll
    for (int q = 0; q < 4; ++q) {
        const float2 t = __half22float2(hp[q]);
        f[2 * q]     = t.x;
        f[2 * q + 1] = t.y;
    }
}

// ---- pass 2: split-channel phased single-sweep render -------------------
__global__ __launch_bounds__(BLOCK, 4) void render_split_kernel(
    const ushort* __restrict__ rec,
    const float*  __restrict__ baryw,
    const int*    __restrict__ tri,
    float*        __restrict__ out)
{
    // grid exactly covers the work: no early returns -> __syncthreads safe.
    const int tidx = threadIdx.x;
    const int lane = tidx & 63;
    const int wid  = tidx >> 6;
    const int h    = lane >> 5;          // channel half: ch 8h..8h+7
    const int q    = lane & 31;
    const int wave = blockIdx.x * (BLOCK / 64) + wid;
    const int p0   = wave * (64 * PIX_PER_LANE / 2) + q * PIX_PER_LANE;

    const int n   = p0 / HW;             // 128-px wave chunk never crosses n
    const int pix = p0 - n * HW;

    // Streamed inputs: nontemporal so they don't evict the face table in L2.
    // Both halves read the same lines (coalescer merges; HBM sees one fetch).
    const i32x4 t4 = __builtin_nontemporal_load(
        reinterpret_cast<const i32x4*>(tri + p0));
    const f32x4* bw = reinterpret_cast<const f32x4*>(baryw + (size_t)p0 * 3);
    const f32x4 b0 = __builtin_nontemporal_load(bw + 0);
    const f32x4 b1 = __builtin_nontemporal_load(bw + 1);
    const f32x4 b2 = __builtin_nontemporal_load(bw + 2);

    float w[PIX_PER_LANE][3] = {
        {b0.x, b0.y, b0.z},
        {b0.w, b1.x, b1.y},
        {b1.z, b1.w, b2.x},
        {b2.y, b2.z, b2.w},
    };
    const int t[PIX_PER_LANE] = {t4.x, t4.y, t4.z, t4.w};

    float vis[PIX_PER_LANE];
#pragma unroll
    for (int j = 0; j < PIX_PER_LANE; ++j) {
        const bool bg = (t[j] < 0);
        vis[j] = bg ? 0.0f : 1.0f;
        // bg pixels never match any phase range (unsigned wrap) -> acc = 0.
        w[j][0] *= vis[j];
        w[j][1] *= vis[j];
        w[j][2] *= vis[j];
    }

    const int4* rec4 = reinterpret_cast<const int4*>(rec);

    float r[PIX_PER_LANE][8];
#pragma unroll
    for (int j = 0; j < PIX_PER_LANE; ++j)
#pragma unroll
        for (int i = 0; i < 8; ++i) r[j][i] = 0.0f;

    // sweep 4 face-range phases; each record line is touched by 3 instrs,
    // shared between the two channel-half lanes -> 3 line lookups/pixel.
#pragma unroll
    for (int ph = 0; ph < NPHASE; ++ph) {
        const int lo = ph * FACES_PER_PHASE;
#pragma unroll
        for (int j = 0; j < PIX_PER_LANE; ++j) {
            // in-range test; t[j] == -1 wraps to huge unsigned -> false
            if ((unsigned)(t[j] - lo) < (unsigned)FACES_PER_PHASE) {
                const int4* rb = rec4 + (size_t)t[j] * 8 + h;
                // slots: vertex v, half h -> 2v + h
                const int4 V0 = rb[0];   // v0, ch 8h..8h+7
                const int4 V1 = rb[2];   // v1
                const int4 V2 = rb[4];   // v2
                float a0[8], a1[8], a2[8];
                h8_to_f8(V0, a0);
                h8_to_f8(V1, a1);
                h8_to_f8(V2, a2);
#pragma unroll
                for (int i = 0; i < 8; ++i)
                    r[j][i] += w[j][0] * a0[i] + w[j][1] * a1[i]
                             + w[j][2] * a2[i];
            }
        }
        // keep the block's waves phase-coherent so machine-wide roughly one
        // 2.56 MB face range is live in L2 at a time
        if (ph != NPHASE - 1) __syncthreads();
    }

    // deferred store burst: lanes 0-31 write plane i, lanes 32-63 plane 8+i
    // in the same instruction (two contiguous 512 B clusters).
    const size_t outbase = (size_t)n * (D + 1) * HW + pix;
#pragma unroll
    for (int i = 0; i < 8; ++i) {
        const int d = h * 8 + i;
        f32x4 o;
        o.x = r[0][i]; o.y = r[1][i]; o.z = r[2][i]; o.w = r[3][i];
        __builtin_nontemporal_store(
            o, reinterpret_cast<f32x4*>(out + outbase + (size_t)d * HW));
    }
    // visibility plane: written once (by the h==0 half only)
    if (h == 0) {
        f32x4 v;
        v.x = vis[0]; v.y = vis[1]; v.z = vis[2]; v.w = vis[3];
        __builtin_nontemporal_store(
            v, reinterpret_cast<f32x4*>(out + outbase + (size_t)D * HW));
    }
}

// ---- fallback: direct fp32 path (R1 kernel) -----------------------------
__global__ __launch_bounds__(BLOCK) void renderer_f32_kernel(
    const float* __restrict__ attrs,
    const float* __restrict__ baryw,
    const int*   __restrict__ tri,
    float*       __restrict__ out)
{
    const int tid = blockIdx.x * BLOCK + threadIdx.x;
    const int p0  = tid * 4;
    if (p0 >= NPIX) return;

    const int n   = p0 / HW;
    const int pix = p0 - n * HW;

    const int4 t4 = *reinterpret_cast<const int4*>(tri + p0);
    const float4* bw = reinterpret_cast<const float4*>(baryw + (size_t)p0 * 3);
    const float4 b0 = bw[0], b1 = bw[1], b2 = bw[2];

    float w[4][3] = {
        {b0.x, b0.y, b0.z},
        {b0.w, b1.x, b1.y},
        {b1.z, b1.w, b2.x},
        {b2.y, b2.z, b2.w},
    };
    const int t[4] = {t4.x, t4.y, t4.z, t4.w};

    float vis[4];
    const float4* abase[4];
#pragma unroll
    for (int j = 0; j < 4; ++j) {
        const bool bg = (t[j] < 0);
        vis[j] = bg ? 0.0f : 1.0f;
        const int tc = bg ? 0 : t[j];
        abase[j] = reinterpret_cast<const float4*>(attrs + (size_t)tc * (3 * D));
        w[j][0] *= vis[j];
        w[j][1] *= vis[j];
        w[j][2] *= vis[j];
    }

    const size_t outbase = (size_t)n * (D + 1) * HW + pix;

#pragma unroll
    for (int c = 0; c < 4; ++c) {
        float r[4][4];
#pragma unroll
        for (int j = 0; j < 4; ++j) {
            const float4 a0 = abase[j][c];
            const float4 a1 = abase[j][4 + c];
            const float4 a2 = abase[j][8 + c];
            r[j][0] = w[j][0] * a0.x + w[j][1] * a1.x + w[j][2] * a2.x;
            r[j][1] = w[j][0] * a0.y + w[j][1] * a1.y + w[j][2] * a2.y;
            r[j][2] = w[j][0] * a0.z + w[j][1] * a1.z + w[j][2] * a2.z;
            r[j][3] = w[j][0] * a0.w + w[j][1] * a1.w + w[j][2] * a2.w;
        }
#pragma unroll
        for (int i = 0; i < 4; ++i) {
            const int d = c * 4 + i;
            float4 o;
            o.x = r[0][i]; o.y = r[1][i]; o.z = r[2][i]; o.w = r[3][i];
            *reinterpret_cast<float4*>(out + outbase + (size_t)d * HW) = o;
        }
    }

    float4 v;
    v.x = vis[0]; v.y = vis[1]; v.z = vis[2]; v.w = vis[3];
    *reinterpret_cast<float4*>(out + outbase + (size_t)D * HW) = v;
}

extern "C" void kernel_launch(void* const* d_in, const int* in_sizes, int n_in,
                              void* d_out, int out_size, void* d_ws, size_t ws_size,
                              hipStream_t stream) {
    const float* attrs = (const float*)d_in[0];
    const float* baryw = (const float*)d_in[1];
    const int*   tri   = (const int*)d_in[2];
    float*       out   = (float*)d_out;

    if (ws_size >= WS_NEEDED) {
        ushort* rec = (ushort*)d_ws;
        const int conv_grid = (NFACES * 6 + BLOCK - 1) / BLOCK;  // 1875
        convert_kernel<<<conv_grid, BLOCK, 0, stream>>>(attrs, rec);
        const int grid = NTHREADS / BLOCK;  // 4096 blocks
        render_split_kernel<<<grid, BLOCK, 0, stream>>>(rec, baryw, tri, out);
    } else {
        const int grid = (NPIX / 4) / BLOCK;
        renderer_f32_kernel<<<grid, BLOCK, 0, stream>>>(attrs, baryw, tri, out);
    }
}

// Round 6
// 210.321 us; speedup vs baseline: 1.4060x; 1.0096x over previous
//
#include <hip/hip_runtime.h>
#include <hip/hip_fp16.h>

// Problem constants (match reference):
//   attrs:    [8, 10000, 3, 16] fp32   (flat face table of 80000 faces x 48 floats)
//   baryw:    [8, 512, 512, 3]  fp32
//   triangle: [8, 512, 512]     int32  (-1 = background; indexes flat [BZ*NF])
//   out:      [8, 17, 512, 512] fp32   (16 interpolated channels + visibility)
//
// R6 = restore R2 (best verified: 206.8 us total, render ~64 us).
// Structure: fp16 128 B-padded records (one L2 line per face), 4-phase
// face-range sweep for L2 residency (2.56 MB live range), single-sweep
// gather (each record read exactly once per pixel), all accumulators in
// registers, deferred nontemporal store burst.
// Post-mortem record of falsified alternatives (keep for future sessions):
//   R3 block-coop LDS gather: 147 us (acc spill to scratch + 32 barriers)
//   R4 wave-coop LDS gather:  ~84 us (LDS round-trip + shfl overhead)
//   R5 split-channel lanes:   ~69 us (same-line lane pair not merged by TA;
//                                     doubled stream-load instruction issue)
// Remaining gap to byte floor (~64 vs ~40 us) is random-gather latency +
// mandatory per-XCD table refill (face ids are uniformly random -> every
// XCD fills every live range; phasing already minimizes this).
constexpr int BZ = 8, NF = 10000, D = 16, HImg = 512, WImg = 512;
constexpr int HW = HImg * WImg;          // 262144
constexpr int NPIX = BZ * HW;            // 2097152
constexpr int NFACES = BZ * NF;          // 80000
constexpr int PIX_PER_THREAD = 4;
constexpr int NTHREADS = NPIX / PIX_PER_THREAD;  // 524288
constexpr int BLOCK = 256;
// fp16 record: 3 vertices x 16 ch x 2 B = 96 B, padded to 128 B (one line).
constexpr size_t REC_USHORTS = 64;       // 128 B / 2
constexpr size_t WS_NEEDED = (size_t)NFACES * 128;

constexpr int NPHASE = 4;
constexpr int FACES_PER_PHASE = NFACES / NPHASE;  // 20000 -> 2.56 MB/phase

typedef float f32x4 __attribute__((ext_vector_type(4)));
typedef int   i32x4 __attribute__((ext_vector_type(4)));

// ---- pass 1: fp32 attrs -> fp16 padded records --------------------------
__global__ __launch_bounds__(BLOCK) void convert_kernel(
    const float* __restrict__ attrs, ushort* __restrict__ rec)
{
    const int tid = blockIdx.x * BLOCK + threadIdx.x;
    if (tid >= NFACES * 6) return;
    const int face = tid / 6;
    const int c    = tid - face * 6;
    const float4* src = reinterpret_cast<const float4*>(
        attrs + (size_t)face * 48 + c * 8);
    const float4 a = src[0], b = src[1];
    __half h[8];
    h[0] = __float2half_rn(a.x); h[1] = __float2half_rn(a.y);
    h[2] = __float2half_rn(a.z); h[3] = __float2half_rn(a.w);
    h[4] = __float2half_rn(b.x); h[5] = __float2half_rn(b.y);
    h[6] = __float2half_rn(b.z); h[7] = __float2half_rn(b.w);
    *reinterpret_cast<int4*>(rec + (size_t)face * REC_USHORTS + c * 8) =
        *reinterpret_cast<const int4*>(h);
}

__device__ inline void h8_to_f8(int4 raw, float f[8]) {
    const __half2* hp = reinterpret_cast<const __half2*>(&raw);
#pragma unroll
    for (int q = 0; q < 4; ++q) {
        const float2 t = __half22float2(hp[q]);
        f[2 * q]     = t.x;
        f[2 * q + 1] = t.y;
    }
}

// ---- pass 2: phased single-sweep render ---------------------------------
__global__ __launch_bounds__(BLOCK, 4) void render_f16_sweep_kernel(
    const ushort* __restrict__ rec,
    const float*  __restrict__ baryw,
    const int*    __restrict__ tri,
    float*        __restrict__ out)
{
    // grid exactly covers NPIX: no early returns -> __syncthreads() is safe.
    const int tid = blockIdx.x * BLOCK + threadIdx.x;
    const int p0  = tid * PIX_PER_THREAD;

    const int n   = p0 / HW;
    const int pix = p0 - n * HW;

    // Streamed inputs: nontemporal so they don't evict the face table in L2.
    const i32x4 t4 = __builtin_nontemporal_load(
        reinterpret_cast<const i32x4*>(tri + p0));
    const f32x4* bw = reinterpret_cast<const f32x4*>(baryw + (size_t)p0 * 3);
    const f32x4 b0 = __builtin_nontemporal_load(bw + 0);
    const f32x4 b1 = __builtin_nontemporal_load(bw + 1);
    const f32x4 b2 = __builtin_nontemporal_load(bw + 2);

    float w[PIX_PER_THREAD][3] = {
        {b0.x, b0.y, b0.z},
        {b0.w, b1.x, b1.y},
        {b1.z, b1.w, b2.x},
        {b2.y, b2.z, b2.w},
    };
    const int t[PIX_PER_THREAD] = {t4.x, t4.y, t4.z, t4.w};

    float vis[PIX_PER_THREAD];
#pragma unroll
    for (int j = 0; j < PIX_PER_THREAD; ++j) {
        const bool bg = (t[j] < 0);
        vis[j] = bg ? 0.0f : 1.0f;
        // bg pixels never match any phase range (unsigned compare vs -1),
        // so their accumulators stay exactly 0.
        w[j][0] *= vis[j];
        w[j][1] *= vis[j];
        w[j][2] *= vis[j];
    }

    const int4* rec4 = reinterpret_cast<const int4*>(rec);

    float r[PIX_PER_THREAD][D];
#pragma unroll
    for (int j = 0; j < PIX_PER_THREAD; ++j)
#pragma unroll
        for (int i = 0; i < D; ++i) r[j][i] = 0.0f;

    // sweep 4 face-range phases; each pixel's record is read exactly ONCE.
#pragma unroll
    for (int ph = 0; ph < NPHASE; ++ph) {
        const int lo = ph * FACES_PER_PHASE;
#pragma unroll
        for (int j = 0; j < PIX_PER_THREAD; ++j) {
            // in-range test; t[j] == -1 wraps to huge unsigned -> false
            if ((unsigned)(t[j] - lo) < (unsigned)FACES_PER_PHASE) {
                const int4* rb = rec4 + (size_t)t[j] * 8;
                // record layout: vertex k occupies int4 slots [2k, 2k+1]
                const int4 V0 = rb[0];   // v0 ch0-7
                const int4 V1 = rb[1];   // v0 ch8-15
                const int4 V2 = rb[2];   // v1 ch0-7
                const int4 V3 = rb[3];   // v1 ch8-15
                const int4 V4 = rb[4];   // v2 ch0-7
                const int4 V5 = rb[5];   // v2 ch8-15
                float a0[8], a1[8], a2[8], a3[8], a4[8], a5[8];
                h8_to_f8(V0, a0); h8_to_f8(V1, a1);
                h8_to_f8(V2, a2); h8_to_f8(V3, a3);
                h8_to_f8(V4, a4); h8_to_f8(V5, a5);
#pragma unroll
                for (int i = 0; i < 8; ++i) {
                    r[j][i]     += w[j][0] * a0[i] + w[j][1] * a2[i]
                                 + w[j][2] * a4[i];
                    r[j][8 + i] += w[j][0] * a1[i] + w[j][1] * a3[i]
                                 + w[j][2] * a5[i];
                }
            }
        }
        // keep the block's waves phase-coherent so machine-wide only one
        // 2.56 MB face range is live in L2 at a time
        if (ph != NPHASE - 1) __syncthreads();
    }

    // deferred store burst: all 17 channels after the gather phases.
    const size_t outbase = (size_t)n * (D + 1) * HW + pix;
#pragma unroll
    for (int d = 0; d < D; ++d) {
        f32x4 o;
        o.x = r[0][d]; o.y = r[1][d]; o.z = r[2][d]; o.w = r[3][d];
        __builtin_nontemporal_store(
            o, reinterpret_cast<f32x4*>(out + outbase + (size_t)d * HW));
    }
    f32x4 v;
    v.x = vis[0]; v.y = vis[1]; v.z = vis[2]; v.w = vis[3];
    __builtin_nontemporal_store(
        v, reinterpret_cast<f32x4*>(out + outbase + (size_t)D * HW));
}

// ---- fallback: direct fp32 path (R1 kernel) -----------------------------
__global__ __launch_bounds__(BLOCK) void renderer_f32_kernel(
    const float* __restrict__ attrs,
    const float* __restrict__ baryw,
    const int*   __restrict__ tri,
    float*       __restrict__ out)
{
    const int tid = blockIdx.x * BLOCK + threadIdx.x;
    const int p0  = tid * PIX_PER_THREAD;
    if (p0 >= NPIX) return;

    const int n   = p0 / HW;
    const int pix = p0 - n * HW;

    const int4 t4 = *reinterpret_cast<const int4*>(tri + p0);
    const float4* bw = reinterpret_cast<const float4*>(baryw + (size_t)p0 * 3);
    const float4 b0 = bw[0], b1 = bw[1], b2 = bw[2];

    float w[PIX_PER_THREAD][3] = {
        {b0.x, b0.y, b0.z},
        {b0.w, b1.x, b1.y},
        {b1.z, b1.w, b2.x},
        {b2.y, b2.z, b2.w},
    };
    const int t[PIX_PER_THREAD] = {t4.x, t4.y, t4.z, t4.w};

    float vis[PIX_PER_THREAD];
    const float4* abase[PIX_PER_THREAD];
#pragma unroll
    for (int j = 0; j < PIX_PER_THREAD; ++j) {
        const bool bg = (t[j] < 0);
        vis[j] = bg ? 0.0f : 1.0f;
        const int tc = bg ? 0 : t[j];
        abase[j] = reinterpret_cast<const float4*>(attrs + (size_t)tc * (3 * D));
        w[j][0] *= vis[j];
        w[j][1] *= vis[j];
        w[j][2] *= vis[j];
    }

    const size_t outbase = (size_t)n * (D + 1) * HW + pix;

#pragma unroll
    for (int c = 0; c < 4; ++c) {
        float r[PIX_PER_THREAD][4];
#pragma unroll
        for (int j = 0; j < PIX_PER_THREAD; ++j) {
            const float4 a0 = abase[j][c];
            const float4 a1 = abase[j][4 + c];
            const float4 a2 = abase[j][8 + c];
            r[j][0] = w[j][0] * a0.x + w[j][1] * a1.x + w[j][2] * a2.x;
            r[j][1] = w[j][0] * a0.y + w[j][1] * a1.y + w[j][2] * a2.y;
            r[j][2] = w[j][0] * a0.z + w[j][1] * a1.z + w[j][2] * a2.z;
            r[j][3] = w[j][0] * a0.w + w[j][1] * a1.w + w[j][2] * a2.w;
        }
#pragma unroll
        for (int i = 0; i < 4; ++i) {
            const int d = c * 4 + i;
            float4 o;
            o.x = r[0][i]; o.y = r[1][i]; o.z = r[2][i]; o.w = r[3][i];
            *reinterpret_cast<float4*>(out + outbase + (size_t)d * HW) = o;
        }
    }

    float4 v;
    v.x = vis[0]; v.y = vis[1]; v.z = vis[2]; v.w = vis[3];
    *reinterpret_cast<float4*>(out + outbase + (size_t)D * HW) = v;
}

extern "C" void kernel_launch(void* const* d_in, const int* in_sizes, int n_in,
                              void* d_out, int out_size, void* d_ws, size_t ws_size,
                              hipStream_t stream) {
    const float* attrs = (const float*)d_in[0];
    const float* baryw = (const float*)d_in[1];
    const int*   tri   = (const int*)d_in[2];
    float*       out   = (float*)d_out;

    const int grid = NTHREADS / BLOCK;  // 2048 blocks

    if (ws_size >= WS_NEEDED) {
        ushort* rec = (ushort*)d_ws;
        const int conv_grid = (NFACES * 6 + BLOCK - 1) / BLOCK;  // 1875
        convert_kernel<<<conv_grid, BLOCK, 0, stream>>>(attrs, rec);
        render_f16_sweep_kernel<<<grid, BLOCK, 0, stream>>>(rec, baryw, tri, out);
    } else {
        renderer_f32_kernel<<<grid, BLOCK, 0, stream>>>(attrs, baryw, tri, out);
    }
}